// Round 9
// baseline (2283.682 us; speedup 1.0000x reference)
//
#include <hip/hip_runtime.h>

#define NBLK 256
#define ROWS 18

__device__ __forceinline__ float dot4(float4 a, float4 b){
  return fmaf(a.x,b.x, fmaf(a.y,b.y, fmaf(a.z,b.z, a.w*b.w)));
}
__device__ __forceinline__ void fma4(float& acc, float4 w, float4 a){
  acc = fmaf(w.x,a.x, fmaf(w.y,a.y, fmaf(w.z,a.z, fmaf(w.w,a.w, acc))));
}
__device__ __forceinline__ float wred(float v){
  #pragma unroll
  for (int m = 32; m >= 1; m >>= 1) v += __shfl_xor(v, m);
  return v;
}

// Agent-scope coherent accessors for small cross-phase activation buffers.
// Bypass the non-coherent per-XCD L2; complete at the coherence point.
__device__ __forceinline__ float gld(const float* p){
  return __hip_atomic_load(p, __ATOMIC_RELAXED, __HIP_MEMORY_SCOPE_AGENT);
}
__device__ __forceinline__ void gst(float* p, float v){
  __hip_atomic_store(p, v, __ATOMIC_RELAXED, __HIP_MEMORY_SCOPE_AGENT);
}

// Tree barrier with epoch broadcast, fence-free (validated R8, absmax 0.0).
__device__ __forceinline__ void gbar(unsigned* bars, int b, unsigned e){
  __syncthreads();
  if (threadIdx.x == 0) {
    unsigned* grp = bars + (b >> 5) * 16;
    __hip_atomic_fetch_add(grp, 1u, __ATOMIC_RELAXED, __HIP_MEMORY_SCOPE_AGENT);
    if ((b & 31) == 0) {
      while (__hip_atomic_load(grp, __ATOMIC_RELAXED, __HIP_MEMORY_SCOPE_AGENT) < 32u * e)
        __builtin_amdgcn_s_sleep(2);
      __hip_atomic_fetch_add(bars + 128, 1u, __ATOMIC_RELAXED, __HIP_MEMORY_SCOPE_AGENT);
      if (b == 0) {
        while (__hip_atomic_load(bars + 128, __ATOMIC_RELAXED, __HIP_MEMORY_SCOPE_AGENT) < 8u * e)
          __builtin_amdgcn_s_sleep(2);
        __hip_atomic_store(bars + 144, e, __ATOMIC_RELAXED, __HIP_MEMORY_SCOPE_AGENT);
      }
    }
    while (__hip_atomic_load(bars + 144, __ATOMIC_RELAXED, __HIP_MEMORY_SCOPE_AGENT) < e)
      __builtin_amdgcn_s_sleep(2);
  }
  __syncthreads();
}

// waves_per_eu(1,2): LDS (75 KB) already limits us to 1 block/CU = 2 waves/EU.
// Without this the allocator targets 128 VGPR (its default) and spills.
__global__ __attribute__((amdgpu_flat_work_group_size(512,512), amdgpu_waves_per_eu(1,2)))
void vox_persist(const int* __restrict__ step, const float* __restrict__ random_,
                 const float* __restrict__ dit_h, const float* __restrict__ feat,
                 const float* __restrict__ cfg, const float* __restrict__ cfgm,
                 const float* __restrict__ t_emb, const float* __restrict__ dt,
                 const float* __restrict__ in_w, const float* __restrict__ in_b,
                 const float* __restrict__ qkv_w, const float* __restrict__ qkv_b,
                 const float* __restrict__ o_w, const float* __restrict__ gu_w,
                 const float* __restrict__ dn_w, const float* __restrict__ op_w,
                 const float* __restrict__ op_b,
                 unsigned* __restrict__ bars,
                 float* __restrict__ hs, float* __restrict__ qkvb,
                 float* __restrict__ gub, float* __restrict__ dout)
{
  __shared__ float sact[ROWS * 1024];
  __shared__ float sredG[16 * ROWS];
  __shared__ float sscale[ROWS];
  __shared__ float sA[8], sB[8];

  const int b    = blockIdx.x;
  const int tid  = threadIdx.x;
  const int w    = tid >> 6;
  const int lane = tid & 63;
  unsigned e = 0;

  // ---------------- prep: hs[18][1024] (coherent stores) ----------------
  if (b < 2) {
    const int c  = b * 512 + tid;
    const int st = step[0];
    const float tv = t_emb[(size_t)st * 1024 + c];
    gst(&hs[0 * 1024 + c], dit_h[c] + tv);
    gst(&hs[9 * 1024 + c], tv);
    #pragma unroll
    for (int p = 0; p < 4; p++) {
      gst(&hs[(1 + p)  * 1024 + c], feat[(size_t)(p)     * 1024 + c]);
      gst(&hs[(10 + p) * 1024 + c], feat[(size_t)(4 + p) * 1024 + c]);
    }
    #pragma unroll
    for (int p = 0; p < 4; p++) {
      float a = in_b[c];
      #pragma unroll
      for (int q4 = 0; q4 < 16; q4++) {
        float4 wv = *(const float4*)&in_w[(size_t)c * 64 + q4 * 4];
        float4 rv = *(const float4*)&random_[p * 64 + q4 * 4];
        a += dot4(wv, rv);
      }
      gst(&hs[(5 + p)  * 1024 + c], a);
      gst(&hs[(14 + p) * 1024 + c], a);
    }
  }

  // phase-static block mappings
  const int cbq = 12 * b;                   // QKV col base (waves 0-5, 2 cols)
  const int cg  = b & 63, ky = b >> 6;      // O / DOWN col-group & K-split
  const int cbo = 16 * cg;
  const int cbg = 16 * b;                   // GU col base (8 waves x 2 cols)
  const int cbd = 16 * cg;

  // stage 18x1024 slice into LDS via coherent 4B loads (coalesced)
  auto stage = [&](const float* src, int stride, int koff) {
    #pragma unroll 6
    for (int t = 0; t < 36; t++) {
      const int i = t * 512 + tid;
      const int r = i >> 10, k = i & 1023;
      sact[i] = gld(&src[(size_t)r * stride + koff + k]);
    }
  };

  gbar(bars, b, ++e);

  for (int l = 0; l < 8; l++) {
    const float* qw = qkv_w + (size_t)l * 3072 * 1024;
    const float* qb = qkv_b + (size_t)l * 3072;
    const float* ow = o_w   + (size_t)l * 1024 * 1024;
    const float* gw = gu_w  + (size_t)l * 8192 * 1024;
    const float* dw = dn_w  + (size_t)l * 1024 * 4096;

    // ============ QKV: qkvb = rms(hs) @ qw^T + qb ============
    {
      stage(hs, 1024, 0);
      __syncthreads();
      if (w >= 6) {                 // waves 6,7: rms of 9 rows each
        #pragma unroll
        for (int t = 0; t < 9; t++) {
          const int r = (w - 6) * 9 + t;
          float ss = 0.f;
          #pragma unroll
          for (int q = 0; q < 4; q++) {
            float4 a = *(const float4*)&sact[r * 1024 + q * 256 + 4 * lane];
            ss += dot4(a, a);
          }
          ss = wred(ss);
          if (lane == 0) sscale[r] = rsqrtf(ss);
        }
      }
      float acc[2][ROWS];
      if (w < 6) {
        #pragma unroll
        for (int c = 0; c < 2; c++)
          #pragma unroll
          for (int r = 0; r < ROWS; r++) acc[c][r] = 0.f;
        #pragma unroll
        for (int ch = 0; ch < 4; ch++) {
          // inline weight loads (lean live range — no cross-stage prefetch)
          float4 wv0 = *(const float4*)&qw[(size_t)(cbq + 2 * w)     * 1024 + ch * 256 + 4 * lane];
          float4 wv1 = *(const float4*)&qw[(size_t)(cbq + 2 * w + 1) * 1024 + ch * 256 + 4 * lane];
          #pragma unroll
          for (int r = 0; r < ROWS; r++) {
            float4 a = *(const float4*)&sact[r * 1024 + ch * 256 + 4 * lane];
            fma4(acc[0][r], wv0, a);
            fma4(acc[1][r], wv1, a);
          }
        }
      }
      __syncthreads();              // sscale ready
      if (w < 6) {
        #pragma unroll
        for (int c = 0; c < 2; c++)
          #pragma unroll
          for (int r = 0; r < ROWS; r++) {
            float v = wred(acc[c][r]);
            if (lane == 0) {
              const int col = cbq + 2 * w + c;
              gst(&qkvb[r * 3072 + col], v * sscale[r] + qb[col]);
            }
          }
      }
    }
    gbar(bars, b, ++e);

    // ============ attn (4 heads in-block) + O K-split, atomic += hs ============
    {
      float4 wbuf[2];
      #pragma unroll
      for (int c = 0; c < 2; c++)
        wbuf[c] = *(const float4*)&ow[(size_t)(cbo + 2 * w + c) * 1024 + ky * 256 + 4 * lane];

      const int bb = w >> 2, hw = w & 3, h = 4 * ky + hw;
      {
        const float ropeInv = powf(10000.f, -(float)(lane & 31) * (1.f / 32.f));
        float q[9], k[9], v[9];
        #pragma unroll
        for (int i = 0; i < 9; i++) {
          const float* base = qkvb + (size_t)(bb * 9 + i) * 3072;
          q[i] = gld(&base[h * 64 + lane]);
          k[i] = gld(&base[1024 + h * 64 + lane]);
          v[i] = gld(&base[2048 + h * 64 + lane]);
        }
        #pragma unroll
        for (int i = 0; i < 9; i++) {
          const float ang = (float)i * ropeInv;
          float sn, cs;
          __sincosf(ang, &sn, &cs);
          const float sgn = (lane < 32) ? -sn : sn;
          const float rq = __shfl_xor(q[i], 32);
          const float rk = __shfl_xor(k[i], 32);
          q[i] = q[i] * cs + rq * sgn;
          k[i] = k[i] * cs + rk * sgn;
        }
        #pragma unroll
        for (int i = 0; i < 9; i++) {
          float sc[9];
          #pragma unroll
          for (int jj = 0; jj < 9; jj++) sc[jj] = wred(q[i] * k[jj]);
          float mx = sc[0];
          #pragma unroll
          for (int jj = 1; jj < 9; jj++) mx = fmaxf(mx, sc[jj]);
          float den = 0.f;
          #pragma unroll
          for (int jj = 0; jj < 9; jj++) { sc[jj] = __expf(sc[jj] - mx); den += sc[jj]; }
          float o = 0.f;
          #pragma unroll
          for (int jj = 0; jj < 9; jj++) o += sc[jj] * v[jj];
          sact[(bb * 9 + i) * 256 + hw * 64 + lane] = o / den;
        }
      }
      __syncthreads();
      float acc[2][ROWS];
      #pragma unroll
      for (int c = 0; c < 2; c++)
        #pragma unroll
        for (int r = 0; r < ROWS; r++) acc[c][r] = 0.f;
      #pragma unroll
      for (int r = 0; r < ROWS; r++) {
        float4 a = *(const float4*)&sact[r * 256 + 4 * lane];
        fma4(acc[0][r], wbuf[0], a);
        fma4(acc[1][r], wbuf[1], a);
      }
      #pragma unroll
      for (int c = 0; c < 2; c++)
        #pragma unroll
        for (int r = 0; r < ROWS; r++) {
          float v2 = wred(acc[c][r]);
          if (lane == 0) atomicAdd(&hs[r * 1024 + cbo + 2 * w + c], v2);
        }
    }
    gbar(bars, b, ++e);

    // ============ gate_up + silu -> gub (gate -> LDS, then up) ============
    {
      const int c0 = cbg + 2 * w;
      stage(hs, 1024, 0);
      __syncthreads();
      #pragma unroll
      for (int t = 0; t < 3; t++) {
        const int r = w + 8 * t;
        if (r < ROWS) {
          float ss = 0.f;
          #pragma unroll
          for (int q = 0; q < 4; q++) {
            float4 a = *(const float4*)&sact[r * 1024 + q * 256 + 4 * lane];
            ss += dot4(a, a);
          }
          ss = wred(ss);
          if (lane == 0) sscale[r] = rsqrtf(ss);
        }
      }
      __syncthreads();

      float acc[2][ROWS];
      // ---- gate (inline weight loads) ----
      #pragma unroll
      for (int c = 0; c < 2; c++)
        #pragma unroll
        for (int r = 0; r < ROWS; r++) acc[c][r] = 0.f;
      #pragma unroll
      for (int ch = 0; ch < 4; ch++) {
        float4 wv0 = *(const float4*)&gw[(size_t)(c0)     * 1024 + ch * 256 + 4 * lane];
        float4 wv1 = *(const float4*)&gw[(size_t)(c0 + 1) * 1024 + ch * 256 + 4 * lane];
        #pragma unroll
        for (int r = 0; r < ROWS; r++) {
          float4 a = *(const float4*)&sact[r * 1024 + ch * 256 + 4 * lane];
          fma4(acc[0][r], wv0, a);
          fma4(acc[1][r], wv1, a);
        }
      }
      #pragma unroll
      for (int c = 0; c < 2; c++)
        #pragma unroll
        for (int r = 0; r < ROWS; r++) {
          float g = wred(acc[c][r]);
          if (lane == 0) sredG[(2 * w + c) * ROWS + r] = g;  // same lane re-reads: no sync
        }
      // ---- up (reuse acc; inline weight loads) ----
      #pragma unroll
      for (int c = 0; c < 2; c++)
        #pragma unroll
        for (int r = 0; r < ROWS; r++) acc[c][r] = 0.f;
      #pragma unroll
      for (int ch = 0; ch < 4; ch++) {
        float4 wv0 = *(const float4*)&gw[(size_t)(4096 + c0)     * 1024 + ch * 256 + 4 * lane];
        float4 wv1 = *(const float4*)&gw[(size_t)(4096 + c0 + 1) * 1024 + ch * 256 + 4 * lane];
        #pragma unroll
        for (int r = 0; r < ROWS; r++) {
          float4 a = *(const float4*)&sact[r * 1024 + ch * 256 + 4 * lane];
          fma4(acc[0][r], wv0, a);
          fma4(acc[1][r], wv1, a);
        }
      }
      #pragma unroll
      for (int c = 0; c < 2; c++)
        #pragma unroll
        for (int r = 0; r < ROWS; r++) {
          float u = wred(acc[c][r]);
          if (lane == 0) {
            const float s = sscale[r];
            const float g = sredG[(2 * w + c) * ROWS + r] * s;
            u *= s;
            gst(&gub[r * 4096 + c0 + c], g / (1.f + __expf(-g)) * u);
          }
        }
    }
    gbar(bars, b, ++e);

    // ============ down K-split, atomic += hs (inline weight loads) ============
    {
      stage(gub, 4096, ky * 1024);
      __syncthreads();
      float acc[2][ROWS];
      #pragma unroll
      for (int c = 0; c < 2; c++)
        #pragma unroll
        for (int r = 0; r < ROWS; r++) acc[c][r] = 0.f;
      #pragma unroll
      for (int ch = 0; ch < 4; ch++) {
        float4 wv0 = *(const float4*)&dw[(size_t)(cbd + 2 * w)     * 4096 + ky * 1024 + ch * 256 + 4 * lane];
        float4 wv1 = *(const float4*)&dw[(size_t)(cbd + 2 * w + 1) * 4096 + ky * 1024 + ch * 256 + 4 * lane];
        #pragma unroll
        for (int r = 0; r < ROWS; r++) {
          float4 a = *(const float4*)&sact[r * 1024 + ch * 256 + 4 * lane];
          fma4(acc[0][r], wv0, a);
          fma4(acc[1][r], wv1, a);
        }
      }
      #pragma unroll
      for (int c = 0; c < 2; c++)
        #pragma unroll
        for (int r = 0; r < ROWS; r++) {
          float v2 = wred(acc[c][r]);
          if (lane == 0) atomicAdd(&hs[r * 1024 + cbd + 2 * w + c], v2);
        }
    }
    gbar(bars, b, ++e);
  }

  // ============ out_proj + CFG combine (block 0) ============
  if (b == 0) {
    for (int i = tid; i < 8192; i += 512) {
      const int r8 = i >> 10, k = i & 1023;
      const int row = (r8 >> 2) * 9 + 5 + (r8 & 3);
      sact[r8 * 1024 + k] = gld(&hs[(size_t)row * 1024 + k]);
    }
    __syncthreads();
    {
      float ss = 0.f;
      #pragma unroll
      for (int qq = 0; qq < 4; qq++) {
        float4 a = *(const float4*)&sact[w * 1024 + 4 * lane + 256 * qq];
        ss += dot4(a, a);
      }
      ss = wred(ss);
      if (lane == 0) sA[w] = rsqrtf(ss);
    }
    __syncthreads();
    float outv;
    {
      const int r8 = tid & 7;
      const int c  = tid >> 3;
      float a0 = 0.f, a1 = 0.f;
      #pragma unroll 4
      for (int k4 = 0; k4 < 128; k4++) {
        a0 += dot4(*(const float4*)&sact[r8 * 1024 + 8 * k4],
                   *(const float4*)&op_w[(size_t)c * 1024 + 8 * k4]);
        a1 += dot4(*(const float4*)&sact[r8 * 1024 + 8 * k4 + 4],
                   *(const float4*)&op_w[(size_t)c * 1024 + 8 * k4 + 4]);
      }
      outv = (a0 + a1) * sA[r8] + op_b[c];
    }
    __syncthreads();
    {
      const int r8 = tid & 7;
      const int c  = tid >> 3;
      sact[r8 * 64 + c] = outv;
    }
    __syncthreads();
    float pos = 0.f, neg = 0.f, dd = 0.f, sq = 0.f;
    if (tid < 256) {
      pos = sact[tid]; neg = sact[256 + tid];
      dd = pos * neg; sq = neg * neg;
    }
    dd = wred(dd); sq = wred(sq);
    if (lane == 0) { sA[w] = dd; sB[w] = sq; }
    __syncthreads();
    if (tid < 256) {
      float dot = 0.f, sqs = 0.f;
      #pragma unroll
      for (int jj = 0; jj < 8; jj++) { dot += sA[jj]; sqs += sB[jj]; }
      const float guided = cfg[0] * pos + cfgm[0] * (dot / sqs) * neg;
      dout[tid] = random_[tid] + guided * dt[step[0]];
    }
  }
}

extern "C" void kernel_launch(void* const* d_in, const int* in_sizes, int n_in,
                              void* d_out, int out_size, void* d_ws, size_t ws_size,
                              hipStream_t stream)
{
  const int*   step    = (const int*)  d_in[0];
  const float* random_ = (const float*)d_in[1];
  const float* dit_h   = (const float*)d_in[2];
  const float* feat    = (const float*)d_in[3];
  const float* cfg     = (const float*)d_in[4];
  const float* cfgm    = (const float*)d_in[5];
  const float* t_emb   = (const float*)d_in[6];
  const float* dt      = (const float*)d_in[7];
  const float* in_w    = (const float*)d_in[8];
  const float* in_b    = (const float*)d_in[9];
  const float* qkv_w   = (const float*)d_in[10];
  const float* qkv_b   = (const float*)d_in[11];
  const float* o_w     = (const float*)d_in[12];
  const float* gu_w    = (const float*)d_in[13];
  const float* dn_w    = (const float*)d_in[14];
  const float* op_w    = (const float*)d_in[15];
  const float* op_b    = (const float*)d_in[16];

  unsigned* bars = (unsigned*)d_ws;                       // [0, 4096)
  float* hs   = (float*)((char*)d_ws + 4096);             // 18*1024
  float* qkvb = hs + ROWS * 1024;                         // 18*3072
  float* gub  = qkvb + ROWS * 3072;                       // 18*4096
  float* dout = (float*)d_out;

  hipMemsetAsync(d_ws, 0, 4096, stream);

  void* args[] = {
    (void*)&step, (void*)&random_, (void*)&dit_h, (void*)&feat, (void*)&cfg,
    (void*)&cfgm, (void*)&t_emb, (void*)&dt, (void*)&in_w, (void*)&in_b,
    (void*)&qkv_w, (void*)&qkv_b, (void*)&o_w, (void*)&gu_w, (void*)&dn_w,
    (void*)&op_w, (void*)&op_b, (void*)&bars,
    (void*)&hs, (void*)&qkvb, (void*)&gub, (void*)&dout
  };
  hipLaunchCooperativeKernel((void*)vox_persist, dim3(NBLK), dim3(512),
                             args, 0, stream);
}

// Round 10
// 1902.648 us; speedup vs baseline: 1.2003x; 1.2003x over previous
//
#include <hip/hip_runtime.h>

#define NBLK 256
#define ROWS 18

__device__ __forceinline__ float dot4(float4 a, float4 b){
  return fmaf(a.x,b.x, fmaf(a.y,b.y, fmaf(a.z,b.z, a.w*b.w)));
}
__device__ __forceinline__ void fma4(float& acc, float4 w, float4 a){
  acc = fmaf(w.x,a.x, fmaf(w.y,a.y, fmaf(w.z,a.z, fmaf(w.w,a.w, acc))));
}
__device__ __forceinline__ float wred(float v){
  #pragma unroll
  for (int m = 32; m >= 1; m >>= 1) v += __shfl_xor(v, m);
  return v;
}

// Uncached producer store: completes at the coherence point, so consumers'
// cold cached reads (fresh addresses) observe it. Drained by __syncthreads.
__device__ __forceinline__ void gst(float* p, float v){
  __hip_atomic_store(p, v, __ATOMIC_RELAXED, __HIP_MEMORY_SCOPE_AGENT);
}

// Fence-free tree barrier with epoch broadcast (ordering validated R8/R9).
// Compiler-only memory barriers pin IR ordering; HW ordering comes from the
// vmcnt drain in __syncthreads before the arrival add.
__device__ __forceinline__ void gbar(unsigned* bars, int b, unsigned e){
  __syncthreads();
  asm volatile("" ::: "memory");
  if (threadIdx.x == 0) {
    unsigned* grp = bars + (b >> 5) * 16;
    __hip_atomic_fetch_add(grp, 1u, __ATOMIC_RELAXED, __HIP_MEMORY_SCOPE_AGENT);
    if ((b & 31) == 0) {
      while (__hip_atomic_load(grp, __ATOMIC_RELAXED, __HIP_MEMORY_SCOPE_AGENT) < 32u * e)
        __builtin_amdgcn_s_sleep(8);
      __hip_atomic_fetch_add(bars + 128, 1u, __ATOMIC_RELAXED, __HIP_MEMORY_SCOPE_AGENT);
      if (b == 0) {
        while (__hip_atomic_load(bars + 128, __ATOMIC_RELAXED, __HIP_MEMORY_SCOPE_AGENT) < 8u * e)
          __builtin_amdgcn_s_sleep(8);
        __hip_atomic_store(bars + 144, e, __ATOMIC_RELAXED, __HIP_MEMORY_SCOPE_AGENT);
      }
    }
    while (__hip_atomic_load(bars + 144, __ATOMIC_RELAXED, __HIP_MEMORY_SCOPE_AGENT) < e)
      __builtin_amdgcn_s_sleep(8);
  }
  asm volatile("" ::: "memory");
  __syncthreads();
}

__global__ __launch_bounds__(512, 1)
void vox_persist(const int* __restrict__ step, const float* __restrict__ random_,
                 const float* __restrict__ dit_h, const float* __restrict__ feat,
                 const float* __restrict__ cfg, const float* __restrict__ cfgm,
                 const float* __restrict__ t_emb, const float* __restrict__ dt,
                 const float* __restrict__ in_w, const float* __restrict__ in_b,
                 const float* __restrict__ qkv_w, const float* __restrict__ qkv_b,
                 const float* __restrict__ o_w, const float* __restrict__ gu_w,
                 const float* __restrict__ dn_w, const float* __restrict__ op_w,
                 const float* __restrict__ op_b,
                 unsigned* __restrict__ bars,
                 float* __restrict__ hs0, float* __restrict__ qkvR,
                 float* __restrict__ hsAR, float* __restrict__ gubR,
                 float* __restrict__ hsBR, float* __restrict__ dout)
{
  __shared__ float sact[ROWS * 1024];
  __shared__ float sredG[16 * ROWS];
  __shared__ float sscale[ROWS];
  __shared__ float sA[8], sB[8];

  const int b    = blockIdx.x;
  const int tid  = threadIdx.x;
  const int w    = tid >> 6;
  const int lane = tid & 63;
  unsigned e = 0;

  // ---------------- prep: hs0[18][1024] (uncached stores) ----------------
  if (b < 2) {
    const int c  = b * 512 + tid;
    const int st = step[0];
    const float tv = t_emb[(size_t)st * 1024 + c];
    gst(&hs0[0 * 1024 + c], dit_h[c] + tv);
    gst(&hs0[9 * 1024 + c], tv);
    #pragma unroll
    for (int p = 0; p < 4; p++) {
      gst(&hs0[(1 + p)  * 1024 + c], feat[(size_t)(p)     * 1024 + c]);
      gst(&hs0[(10 + p) * 1024 + c], feat[(size_t)(4 + p) * 1024 + c]);
    }
    #pragma unroll
    for (int p = 0; p < 4; p++) {
      float a = in_b[c];
      #pragma unroll
      for (int q4 = 0; q4 < 16; q4++) {
        float4 wv = *(const float4*)&in_w[(size_t)c * 64 + q4 * 4];
        float4 rv = *(const float4*)&random_[p * 64 + q4 * 4];
        a += dot4(wv, rv);
      }
      gst(&hs0[(5 + p)  * 1024 + c], a);
      gst(&hs0[(14 + p) * 1024 + c], a);
    }
  }

  // phase-static block mappings
  const int cbq = 12 * b;                   // QKV col base (waves 0-5, 2 cols)
  const int cg  = b & 63, ky = b >> 6;      // attnO / DOWN col-group & K-split
  const int cbo = 16 * cg;
  const int cbg = 16 * b;                   // GU col base (8 waves x 2 cols)
  const int cbd = 16 * cg;

  // cached, coalesced float4 staging (addresses are always phase-fresh)
  auto stage = [&](const float* src, int stride, int koff) {
    #pragma unroll 3
    for (int t = 0; t < 9; t++) {
      const int t4 = t * 512 + tid;
      const int r  = t4 >> 8;
      const int k4 = (t4 & 255) * 4;
      *(float4*)&sact[r * 1024 + k4] = *(const float4*)&src[(size_t)r * stride + koff + k4];
    }
  };

  gbar(bars, b, ++e);

  for (int l = 0; l < 8; l++) {
    const float* qw = qkv_w + (size_t)l * 3072 * 1024;
    const float* qb = qkv_b + (size_t)l * 3072;
    const float* ow = o_w   + (size_t)l * 1024 * 1024;
    const float* gw = gu_w  + (size_t)l * 8192 * 1024;
    const float* dw = dn_w  + (size_t)l * 1024 * 4096;

    float* qkv_l = qkvR + (size_t)l * ROWS * 3072;
    float* hsA_l = hsAR + (size_t)l * ROWS * 1024;
    float* gub_l = gubR + (size_t)l * ROWS * 4096;
    float* hsB_l = hsBR + (size_t)l * ROWS * 1024;
    const float* hs_in = (l == 0) ? hs0 : hsBR + (size_t)(l - 1) * ROWS * 1024;

    // ============ QKV: qkv_l = rms(hs_in) @ qw^T + qb; copy hs_in -> hsA_l ============
    {
      stage(hs_in, 1024, 0);
      __syncthreads();
      // carry residual forward from LDS (hsA_l becomes the attnO atomic target)
      if (tid < 72) { const int i = b * 72 + tid; gst(&hsA_l[i], sact[i]); }
      if (w >= 6) {                 // waves 6,7: rms of 9 rows each
        #pragma unroll
        for (int t = 0; t < 9; t++) {
          const int r = (w - 6) * 9 + t;
          float ss = 0.f;
          #pragma unroll
          for (int q = 0; q < 4; q++) {
            float4 a = *(const float4*)&sact[r * 1024 + q * 256 + 4 * lane];
            ss += dot4(a, a);
          }
          ss = wred(ss);
          if (lane == 0) sscale[r] = rsqrtf(ss);
        }
      }
      float acc[2][ROWS];
      if (w < 6) {
        #pragma unroll
        for (int c = 0; c < 2; c++)
          #pragma unroll
          for (int r = 0; r < ROWS; r++) acc[c][r] = 0.f;
        #pragma unroll
        for (int ch = 0; ch < 4; ch++) {
          float4 wv0 = *(const float4*)&qw[(size_t)(cbq + 2 * w)     * 1024 + ch * 256 + 4 * lane];
          float4 wv1 = *(const float4*)&qw[(size_t)(cbq + 2 * w + 1) * 1024 + ch * 256 + 4 * lane];
          #pragma unroll
          for (int r = 0; r < ROWS; r++) {
            float4 a = *(const float4*)&sact[r * 1024 + ch * 256 + 4 * lane];
            fma4(acc[0][r], wv0, a);
            fma4(acc[1][r], wv1, a);
          }
        }
      }
      __syncthreads();              // sscale ready
      if (w < 6) {
        #pragma unroll
        for (int c = 0; c < 2; c++)
          #pragma unroll
          for (int r = 0; r < ROWS; r++) {
            float v = wred(acc[c][r]);
            if (lane == 0) {
              const int col = cbq + 2 * w + c;
              gst(&qkv_l[r * 3072 + col], v * sscale[r] + qb[col]);
            }
          }
      }
    }
    gbar(bars, b, ++e);

    // ============ attn (4 heads in-block) + O K-split, atomicAdd -> hsA_l ============
    {
      float4 wbuf[2];
      #pragma unroll
      for (int c = 0; c < 2; c++)
        wbuf[c] = *(const float4*)&ow[(size_t)(cbo + 2 * w + c) * 1024 + ky * 256 + 4 * lane];

      const int bb = w >> 2, hw = w & 3, h = 4 * ky + hw;
      {
        const float ropeInv = powf(10000.f, -(float)(lane & 31) * (1.f / 32.f));
        float q[9], k[9], v[9];
        #pragma unroll
        for (int i = 0; i < 9; i++) {
          const float* base = qkv_l + (size_t)(bb * 9 + i) * 3072;
          q[i] = base[h * 64 + lane];
          k[i] = base[1024 + h * 64 + lane];
          v[i] = base[2048 + h * 64 + lane];
        }
        #pragma unroll
        for (int i = 0; i < 9; i++) {
          const float ang = (float)i * ropeInv;
          float sn, cs;
          __sincosf(ang, &sn, &cs);
          const float sgn = (lane < 32) ? -sn : sn;
          const float rq = __shfl_xor(q[i], 32);
          const float rk = __shfl_xor(k[i], 32);
          q[i] = q[i] * cs + rq * sgn;
          k[i] = k[i] * cs + rk * sgn;
        }
        #pragma unroll
        for (int i = 0; i < 9; i++) {
          float sc[9];
          #pragma unroll
          for (int jj = 0; jj < 9; jj++) sc[jj] = wred(q[i] * k[jj]);
          float mx = sc[0];
          #pragma unroll
          for (int jj = 1; jj < 9; jj++) mx = fmaxf(mx, sc[jj]);
          float den = 0.f;
          #pragma unroll
          for (int jj = 0; jj < 9; jj++) { sc[jj] = __expf(sc[jj] - mx); den += sc[jj]; }
          float o = 0.f;
          #pragma unroll
          for (int jj = 0; jj < 9; jj++) o += sc[jj] * v[jj];
          sact[(bb * 9 + i) * 256 + hw * 64 + lane] = o / den;
        }
      }
      __syncthreads();
      float acc[2][ROWS];
      #pragma unroll
      for (int c = 0; c < 2; c++)
        #pragma unroll
        for (int r = 0; r < ROWS; r++) acc[c][r] = 0.f;
      #pragma unroll
      for (int r = 0; r < ROWS; r++) {
        float4 a = *(const float4*)&sact[r * 256 + 4 * lane];
        fma4(acc[0][r], wbuf[0], a);
        fma4(acc[1][r], wbuf[1], a);
      }
      #pragma unroll
      for (int c = 0; c < 2; c++)
        #pragma unroll
        for (int r = 0; r < ROWS; r++) {
          float v2 = wred(acc[c][r]);
          if (lane == 0) atomicAdd(&hsA_l[r * 1024 + cbo + 2 * w + c], v2);
        }
    }
    gbar(bars, b, ++e);

    // ============ gate_up + silu -> gub_l; copy hsA_l -> hsB_l ============
    {
      const int c0 = cbg + 2 * w;
      stage(hsA_l, 1024, 0);
      __syncthreads();
      if (tid < 72) { const int i = b * 72 + tid; gst(&hsB_l[i], sact[i]); }
      #pragma unroll
      for (int t = 0; t < 3; t++) {
        const int r = w + 8 * t;
        if (r < ROWS) {
          float ss = 0.f;
          #pragma unroll
          for (int q = 0; q < 4; q++) {
            float4 a = *(const float4*)&sact[r * 1024 + q * 256 + 4 * lane];
            ss += dot4(a, a);
          }
          ss = wred(ss);
          if (lane == 0) sscale[r] = rsqrtf(ss);
        }
      }
      __syncthreads();

      float acc[2][ROWS];
      // ---- gate ----
      #pragma unroll
      for (int c = 0; c < 2; c++)
        #pragma unroll
        for (int r = 0; r < ROWS; r++) acc[c][r] = 0.f;
      #pragma unroll
      for (int ch = 0; ch < 4; ch++) {
        float4 wv0 = *(const float4*)&gw[(size_t)(c0)     * 1024 + ch * 256 + 4 * lane];
        float4 wv1 = *(const float4*)&gw[(size_t)(c0 + 1) * 1024 + ch * 256 + 4 * lane];
        #pragma unroll
        for (int r = 0; r < ROWS; r++) {
          float4 a = *(const float4*)&sact[r * 1024 + ch * 256 + 4 * lane];
          fma4(acc[0][r], wv0, a);
          fma4(acc[1][r], wv1, a);
        }
      }
      #pragma unroll
      for (int c = 0; c < 2; c++)
        #pragma unroll
        for (int r = 0; r < ROWS; r++) {
          float g = wred(acc[c][r]);
          if (lane == 0) sredG[(2 * w + c) * ROWS + r] = g;  // same lane re-reads
        }
      // ---- up (reuse acc) ----
      #pragma unroll
      for (int c = 0; c < 2; c++)
        #pragma unroll
        for (int r = 0; r < ROWS; r++) acc[c][r] = 0.f;
      #pragma unroll
      for (int ch = 0; ch < 4; ch++) {
        float4 wv0 = *(const float4*)&gw[(size_t)(4096 + c0)     * 1024 + ch * 256 + 4 * lane];
        float4 wv1 = *(const float4*)&gw[(size_t)(4096 + c0 + 1) * 1024 + ch * 256 + 4 * lane];
        #pragma unroll
        for (int r = 0; r < ROWS; r++) {
          float4 a = *(const float4*)&sact[r * 1024 + ch * 256 + 4 * lane];
          fma4(acc[0][r], wv0, a);
          fma4(acc[1][r], wv1, a);
        }
      }
      #pragma unroll
      for (int c = 0; c < 2; c++)
        #pragma unroll
        for (int r = 0; r < ROWS; r++) {
          float u = wred(acc[c][r]);
          if (lane == 0) {
            const float s = sscale[r];
            const float g = sredG[(2 * w + c) * ROWS + r] * s;
            u *= s;
            gst(&gub_l[r * 4096 + c0 + c], g / (1.f + __expf(-g)) * u);
          }
        }
    }
    gbar(bars, b, ++e);

    // ============ down K-split, atomicAdd -> hsB_l ============
    {
      stage(gub_l, 4096, ky * 1024);
      __syncthreads();
      float acc[2][ROWS];
      #pragma unroll
      for (int c = 0; c < 2; c++)
        #pragma unroll
        for (int r = 0; r < ROWS; r++) acc[c][r] = 0.f;
      #pragma unroll
      for (int ch = 0; ch < 4; ch++) {
        float4 wv0 = *(const float4*)&dw[(size_t)(cbd + 2 * w)     * 4096 + ky * 1024 + ch * 256 + 4 * lane];
        float4 wv1 = *(const float4*)&dw[(size_t)(cbd + 2 * w + 1) * 4096 + ky * 1024 + ch * 256 + 4 * lane];
        #pragma unroll
        for (int r = 0; r < ROWS; r++) {
          float4 a = *(const float4*)&sact[r * 1024 + ch * 256 + 4 * lane];
          fma4(acc[0][r], wv0, a);
          fma4(acc[1][r], wv1, a);
        }
      }
      #pragma unroll
      for (int c = 0; c < 2; c++)
        #pragma unroll
        for (int r = 0; r < ROWS; r++) {
          float v2 = wred(acc[c][r]);
          if (lane == 0) atomicAdd(&hsB_l[r * 1024 + cbd + 2 * w + c], v2);
        }
    }
    gbar(bars, b, ++e);
  }

  // ============ out_proj + CFG combine (block 0; reads hsB_7, fresh) ============
  if (b == 0) {
    const float* hsf = hsBR + (size_t)7 * ROWS * 1024;
    for (int t4 = tid; t4 < 2048; t4 += 512) {
      const int r8 = t4 / 256;
      const int k4 = (t4 % 256) * 4;
      const int row = (r8 >> 2) * 9 + 5 + (r8 & 3);
      *(float4*)&sact[r8 * 1024 + k4] = *(const float4*)&hsf[(size_t)row * 1024 + k4];
    }
    __syncthreads();
    {
      float ss = 0.f;
      #pragma unroll
      for (int qq = 0; qq < 4; qq++) {
        float4 a = *(const float4*)&sact[w * 1024 + 4 * lane + 256 * qq];
        ss += dot4(a, a);
      }
      ss = wred(ss);
      if (lane == 0) sA[w] = rsqrtf(ss);
    }
    __syncthreads();
    float outv;
    {
      const int r8 = tid & 7;
      const int c  = tid >> 3;
      float a0 = 0.f, a1 = 0.f;
      #pragma unroll 4
      for (int k4 = 0; k4 < 128; k4++) {
        a0 += dot4(*(const float4*)&sact[r8 * 1024 + 8 * k4],
                   *(const float4*)&op_w[(size_t)c * 1024 + 8 * k4]);
        a1 += dot4(*(const float4*)&sact[r8 * 1024 + 8 * k4 + 4],
                   *(const float4*)&op_w[(size_t)c * 1024 + 8 * k4 + 4]);
      }
      outv = (a0 + a1) * sA[r8] + op_b[c];
    }
    __syncthreads();
    {
      const int r8 = tid & 7;
      const int c  = tid >> 3;
      sact[r8 * 64 + c] = outv;
    }
    __syncthreads();
    float pos = 0.f, neg = 0.f, dd = 0.f, sq = 0.f;
    if (tid < 256) {
      pos = sact[tid]; neg = sact[256 + tid];
      dd = pos * neg; sq = neg * neg;
    }
    dd = wred(dd); sq = wred(sq);
    if (lane == 0) { sA[w] = dd; sB[w] = sq; }
    __syncthreads();
    if (tid < 256) {
      float dot = 0.f, sqs = 0.f;
      #pragma unroll
      for (int jj = 0; jj < 8; jj++) { dot += sA[jj]; sqs += sB[jj]; }
      const float guided = cfg[0] * pos + cfgm[0] * (dot / sqs) * neg;
      dout[tid] = random_[tid] + guided * dt[step[0]];
    }
  }
}

extern "C" void kernel_launch(void* const* d_in, const int* in_sizes, int n_in,
                              void* d_out, int out_size, void* d_ws, size_t ws_size,
                              hipStream_t stream)
{
  const int*   step    = (const int*)  d_in[0];
  const float* random_ = (const float*)d_in[1];
  const float* dit_h   = (const float*)d_in[2];
  const float* feat    = (const float*)d_in[3];
  const float* cfg     = (const float*)d_in[4];
  const float* cfgm    = (const float*)d_in[5];
  const float* t_emb   = (const float*)d_in[6];
  const float* dt      = (const float*)d_in[7];
  const float* in_w    = (const float*)d_in[8];
  const float* in_b    = (const float*)d_in[9];
  const float* qkv_w   = (const float*)d_in[10];
  const float* qkv_b   = (const float*)d_in[11];
  const float* o_w     = (const float*)d_in[12];
  const float* gu_w    = (const float*)d_in[13];
  const float* dn_w    = (const float*)d_in[14];
  const float* op_w    = (const float*)d_in[15];
  const float* op_b    = (const float*)d_in[16];

  // rotating buffers: each address written by one phase, first-read by the next
  unsigned* bars = (unsigned*)d_ws;                        // 4 KB
  float* hs0  = (float*)((char*)d_ws + 4096);              // 18432
  float* qkvR = hs0  + ROWS * 1024;                        // 8 x 55296
  float* hsAR = qkvR + 8 * ROWS * 3072;                    // 8 x 18432
  float* gubR = hsAR + 8 * ROWS * 1024;                    // 8 x 73728
  float* hsBR = gubR + 8 * ROWS * 4096;                    // 8 x 18432
  float* dout = (float*)d_out;

  hipMemsetAsync(d_ws, 0, 4096, stream);

  void* args[] = {
    (void*)&step, (void*)&random_, (void*)&dit_h, (void*)&feat, (void*)&cfg,
    (void*)&cfgm, (void*)&t_emb, (void*)&dt, (void*)&in_w, (void*)&in_b,
    (void*)&qkv_w, (void*)&qkv_b, (void*)&o_w, (void*)&gu_w, (void*)&dn_w,
    (void*)&op_w, (void*)&op_b, (void*)&bars,
    (void*)&hs0, (void*)&qkvR, (void*)&hsAR, (void*)&gubR, (void*)&hsBR,
    (void*)&dout
  };
  hipLaunchCooperativeKernel((void*)vox_persist, dim3(NBLK), dim3(512),
                             args, 0, stream);
}

// Round 11
// 1134.098 us; speedup vs baseline: 2.0137x; 1.6777x over previous
//
#include <hip/hip_runtime.h>

#define NBLK 256
#define ROWS 18
#define HID 1024

__device__ __forceinline__ float dot4(float4 a, float4 b){
  return fmaf(a.x,b.x, fmaf(a.y,b.y, fmaf(a.z,b.z, a.w*b.w)));
}
__device__ __forceinline__ void fma4(float& acc, float4 w, float4 a){
  acc = fmaf(w.x,a.x, fmaf(w.y,a.y, fmaf(w.z,a.z, fmaf(w.w,a.w, acc))));
}

// Tree barrier with epoch broadcast + full fence pair (R2-equivalent
// visibility semantics, R7-style low-contention arrival/spin).
__device__ __forceinline__ void gbar(unsigned* bars, int b, unsigned e){
  __syncthreads();
  if (threadIdx.x == 0) {
    __threadfence();   // release (as grid.sync does)
    unsigned* grp = bars + (b >> 5) * 16;
    __hip_atomic_fetch_add(grp, 1u, __ATOMIC_RELAXED, __HIP_MEMORY_SCOPE_AGENT);
    if ((b & 31) == 0) {
      while (__hip_atomic_load(grp, __ATOMIC_RELAXED, __HIP_MEMORY_SCOPE_AGENT) < 32u * e)
        __builtin_amdgcn_s_sleep(4);
      __hip_atomic_fetch_add(bars + 128, 1u, __ATOMIC_RELAXED, __HIP_MEMORY_SCOPE_AGENT);
      if (b == 0) {
        while (__hip_atomic_load(bars + 128, __ATOMIC_RELAXED, __HIP_MEMORY_SCOPE_AGENT) < 8u * e)
          __builtin_amdgcn_s_sleep(4);
        __hip_atomic_store(bars + 144, e, __ATOMIC_RELAXED, __HIP_MEMORY_SCOPE_AGENT);
      }
    }
    while (__hip_atomic_load(bars + 144, __ATOMIC_RELAXED, __HIP_MEMORY_SCOPE_AGENT) < e)
      __builtin_amdgcn_s_sleep(4);
    __threadfence();   // acquire
  }
  __syncthreads();
}

// ===== R2's phase_gemm, verbatim (clean codegen, verified correct) =====
template<int K, int ASTR, int PK, int NP, int NWACT, int NC, int ACT, int CSTR,
         bool RMS, bool BIAS, bool ATOMIC>
__device__ __forceinline__ void phase_gemm(
    const float* __restrict__ Wt, const float* __restrict__ act,
    const float* __restrict__ bias, float* __restrict__ outp,
    float* __restrict__ sact, float* __restrict__ sred, float* __restrict__ sscale,
    int cb, int k0)
{
  const int tid  = threadIdx.x;
  const int w    = tid >> 6;
  const int lane = tid & 63;

  float acc[NC][ROWS];
  #pragma unroll
  for (int i = 0; i < NC; i++)
    #pragma unroll
    for (int r = 0; r < ROWS; r++) acc[i][r] = 0.f;

  float rs[3] = {0.f, 0.f, 0.f};

  for (int p = 0; p < NP; p++) {
    __syncthreads();
    constexpr int N4 = ROWS * PK / 4;
    for (int t4 = tid; t4 < N4; t4 += 512) {
      const int r  = t4 / (PK / 4);
      const int k4 = (t4 % (PK / 4)) * 4;
      const int kg = k0 + p * PK + k4;
      float4 v;
      if (ACT == 0) {
        v = *(const float4*)&act[(size_t)r * ASTR + kg];
      } else {
        float4 gv = *(const float4*)&act[(size_t)r * ASTR + kg];
        float4 uv = *(const float4*)&act[(size_t)r * ASTR + 4096 + kg];
        v.x = gv.x / (1.f + __expf(-gv.x)) * uv.x;
        v.y = gv.y / (1.f + __expf(-gv.y)) * uv.y;
        v.z = gv.z / (1.f + __expf(-gv.z)) * uv.z;
        v.w = gv.w / (1.f + __expf(-gv.w)) * uv.w;
      }
      *(float4*)&sact[r * PK + k4] = v;
    }
    __syncthreads();

    if (RMS) {
      #pragma unroll
      for (int t = 0; t < 3; t++) {
        const int r = w + 8 * t;
        if (r < ROWS) {
          float ss = 0.f;
          #pragma unroll
          for (int kk = 4 * lane; kk < PK; kk += 256) {
            float4 a = *(const float4*)&sact[r * PK + kk];
            ss += dot4(a, a);
          }
          rs[t] += ss;
        }
      }
    }

    if (w < NWACT) {
      constexpr int NCH = PK / 256;
      #pragma unroll
      for (int ch = 0; ch < NCH; ch++) {
        const int kk = ch * 256 + 4 * lane;
        float4 wv[NC];
        #pragma unroll
        for (int i = 0; i < NC; i++)
          wv[i] = *(const float4*)&Wt[(size_t)(cb + w * NC + i) * K + k0 + p * PK + kk];
        #pragma unroll
        for (int r = 0; r < ROWS; r++) {
          float4 a = *(const float4*)&sact[r * PK + kk];
          #pragma unroll
          for (int i = 0; i < NC; i++)
            acc[i][r] = fmaf(wv[i].x, a.x, fmaf(wv[i].y, a.y,
                        fmaf(wv[i].z, a.z, fmaf(wv[i].w, a.w, acc[i][r]))));
        }
      }
    }
  }

  if (RMS) {
    #pragma unroll
    for (int t = 0; t < 3; t++) {
      const int r = w + 8 * t;
      if (r < ROWS) {
        float ss = rs[t];
        #pragma unroll
        for (int m = 32; m >= 1; m >>= 1) ss += __shfl_xor(ss, m);
        if (lane == 0) sscale[r] = rsqrtf(ss);
      }
    }
  }

  if (w < NWACT) {
    #pragma unroll
    for (int i = 0; i < NC; i++)
      #pragma unroll
      for (int r = 0; r < ROWS; r++) {
        float v = acc[i][r];
        #pragma unroll
        for (int m = 32; m >= 1; m >>= 1) v += __shfl_xor(v, m);
        if (lane == 0) sred[(w * NC + i) * ROWS + r] = v;
      }
  }
  __syncthreads();

  constexpr int TOT = NWACT * NC * ROWS;
  for (int t = tid; t < TOT; t += 512) {
    const int r    = t % ROWS;
    const int rest = t / ROWS;
    const int c    = cb + rest;
    float v = sred[rest * ROWS + r];
    if (RMS)  v *= sscale[r];
    if (BIAS) v += bias[c];
    if (ATOMIC) atomicAdd(&outp[(size_t)r * CSTR + c], v);
    else        outp[(size_t)r * CSTR + c] = v;
  }
}

__global__ __launch_bounds__(512, 2)
void vox_persist(const int* __restrict__ step, const float* __restrict__ random_,
                 const float* __restrict__ dit_h, const float* __restrict__ feat,
                 const float* __restrict__ cfg, const float* __restrict__ cfgm,
                 const float* __restrict__ t_emb, const float* __restrict__ dt,
                 const float* __restrict__ in_w, const float* __restrict__ in_b,
                 const float* __restrict__ qkv_w, const float* __restrict__ qkv_b,
                 const float* __restrict__ o_w, const float* __restrict__ gu_w,
                 const float* __restrict__ dn_w, const float* __restrict__ op_w,
                 const float* __restrict__ op_b,
                 unsigned* __restrict__ bars,
                 float* __restrict__ hs, float* __restrict__ qkvb,
                 float* __restrict__ attnb, float* __restrict__ gub,
                 float* __restrict__ outtmp, float* __restrict__ dout)
{
  __shared__ float sact[ROWS * 512];
  __shared__ float sred[8 * 4 * ROWS];
  __shared__ float sscale[ROWS];
  __shared__ float smisc[144];

  const int b   = blockIdx.x;
  const int tid = threadIdx.x;
  unsigned e = 0;

  // ================= prep: build hs[18][1024] (verbatim R2) =================
  if (b < 2) {
    const int c  = b * 512 + tid;
    const int st = step[0];
    const float tv = t_emb[(size_t)st * HID + c];
    hs[0 * HID + c] = dit_h[c] + tv;
    hs[9 * HID + c] = tv;
    #pragma unroll
    for (int p = 0; p < 4; p++) {
      hs[(1 + p) * HID + c]  = feat[(size_t)(0 * 4 + p) * HID + c];
      hs[(10 + p) * HID + c] = feat[(size_t)(1 * 4 + p) * HID + c];
    }
    #pragma unroll
    for (int p = 0; p < 4; p++) {
      float a = in_b[c];
      #pragma unroll
      for (int q4 = 0; q4 < 16; q4++) {
        float4 wv = *(const float4*)&in_w[(size_t)c * 64 + q4 * 4];
        float4 rv = *(const float4*)&random_[p * 64 + q4 * 4];
        a += dot4(wv, rv);
      }
      hs[(5 + p) * HID + c]  = a;
      hs[(14 + p) * HID + c] = a;
    }
  }
  gbar(bars, b, ++e);

  // ================= 8 transformer layers (verbatim R2 phases) =================
  for (int i = 0; i < 8; i++) {
    const float* qw = qkv_w + (size_t)i * 3072 * 1024;
    const float* qb = qkv_b + (size_t)i * 3072;
    const float* ow = o_w   + (size_t)i * 1024 * 1024;
    const float* gw = gu_w  + (size_t)i * 8192 * 1024;
    const float* dw = dn_w  + (size_t)i * 1024 * 4096;

    phase_gemm<1024, 1024, 512, 2, 6, 2, 0, 3072, true, true, false>
        (qw, hs, qb, qkvb, sact, sred, sscale, b * 12, 0);
    gbar(bars, b, ++e);

    if (b < 32 && tid < 64) {
      const int bb = b >> 4, h = b & 15, d = tid;
      const float* base = qkvb + (size_t)bb * 9 * 3072;
      float q[9], k[9], v[9];
      #pragma unroll
      for (int ii = 0; ii < 9; ii++) {
        q[ii] = base[ii * 3072 + h * 64 + d];
        k[ii] = base[ii * 3072 + (16 + h) * 64 + d];
        v[ii] = base[ii * 3072 + (32 + h) * 64 + d];
      }
      const int j = d & 31;
      const float inv = powf(10000.f, -(float)j * (1.f / 32.f));
      #pragma unroll
      for (int ii = 0; ii < 9; ii++) {
        const float ang = (float)ii * inv;
        float sn, cs;
        __sincosf(ang, &sn, &cs);
        const float sgn = (d < 32) ? -sn : sn;
        const float rq = __shfl_xor(q[ii], 32);
        const float rk = __shfl_xor(k[ii], 32);
        q[ii] = q[ii] * cs + rq * sgn;
        k[ii] = k[ii] * cs + rk * sgn;
      }
      float* obase = attnb + (size_t)bb * 9 * HID + h * 64 + d;
      for (int ii = 0; ii < 9; ii++) {
        float sc[9];
        #pragma unroll
        for (int jj = 0; jj < 9; jj++) {
          float p = q[ii] * k[jj];
          #pragma unroll
          for (int m = 32; m >= 1; m >>= 1) p += __shfl_xor(p, m);
          sc[jj] = p;
        }
        float mx = sc[0];
        #pragma unroll
        for (int jj = 1; jj < 9; jj++) mx = fmaxf(mx, sc[jj]);
        float den = 0.f;
        #pragma unroll
        for (int jj = 0; jj < 9; jj++) { sc[jj] = __expf(sc[jj] - mx); den += sc[jj]; }
        float o = 0.f;
        #pragma unroll
        for (int jj = 0; jj < 9; jj++) o += sc[jj] * v[jj];
        obase[ii * HID] = o / den;
      }
    }
    gbar(bars, b, ++e);

    phase_gemm<1024, 1024, 256, 1, 8, 2, 0, 1024, false, false, true>
        (ow, attnb, nullptr, hs, sact, sred, sscale, (b & 63) * 16, (b >> 6) * 256);
    gbar(bars, b, ++e);

    phase_gemm<1024, 1024, 512, 2, 8, 4, 0, 8192, true, false, false>
        (gw, hs, nullptr, gub, sact, sred, sscale, b * 32, 0);
    gbar(bars, b, ++e);

    phase_gemm<4096, 8192, 512, 2, 8, 2, 1, 1024, false, false, true>
        (dw, gub, nullptr, hs, sact, sred, sscale, (b & 63) * 16, (b >> 6) * 1024);
    gbar(bars, b, ++e);
  }

  // ================= out_proj (blocks 0..63) =================
  if (b < 64) {
    const int c = b;
    const int w = tid >> 6, lane = tid & 63;
    float* la = smisc;
    float* ls = smisc + 64;
    const float2 wv = ((const float2*)&op_w[(size_t)c * HID])[tid];
    #pragma unroll
    for (int r8 = 0; r8 < 8; r8++) {
      const int row = (r8 >> 2) * 9 + 5 + (r8 & 3);
      const float2 hv = ((const float2*)&hs[(size_t)row * HID])[tid];
      float a = fmaf(wv.x, hv.x, wv.y * hv.y);
      float s = fmaf(hv.x, hv.x, hv.y * hv.y);
      #pragma unroll
      for (int m = 32; m >= 1; m >>= 1) { a += __shfl_xor(a, m); s += __shfl_xor(s, m); }
      if (lane == 0) { la[r8 * 8 + w] = a; ls[r8 * 8 + w] = s; }
    }
    __syncthreads();
    if (tid < 8) {
      float a = 0.f, s = 0.f;
      #pragma unroll
      for (int jj = 0; jj < 8; jj++) { a += la[tid * 8 + jj]; s += ls[tid * 8 + jj]; }
      outtmp[tid * 64 + c] = a * rsqrtf(s) + op_b[c];
    }
  }
  gbar(bars, b, ++e);

  // ================= CFG combine (block 0) =================
  if (b == 0) {
    const int w = tid >> 6, lane = tid & 63;
    float pos = 0.f, neg = 0.f, d = 0.f, s = 0.f;
    if (tid < 256) {
      pos = outtmp[tid]; neg = outtmp[256 + tid];
      d = pos * neg; s = neg * neg;
    }
    #pragma unroll
    for (int m = 32; m >= 1; m >>= 1) { d += __shfl_xor(d, m); s += __shfl_xor(s, m); }
    float* ld  = smisc;
    float* lsq = smisc + 8;
    if (lane == 0) { ld[w] = d; lsq[w] = s; }
    __syncthreads();
    if (tid < 256) {
      float dot = 0.f, sq = 0.f;
      #pragma unroll
      for (int jj = 0; jj < 8; jj++) { dot += ld[jj]; sq += lsq[jj]; }
      const float guided = cfg[0] * pos + cfgm[0] * (dot / sq) * neg;
      dout[tid] = random_[tid] + guided * dt[step[0]];
    }
  }
}

extern "C" void kernel_launch(void* const* d_in, const int* in_sizes, int n_in,
                              void* d_out, int out_size, void* d_ws, size_t ws_size,
                              hipStream_t stream)
{
  const int*   step    = (const int*)  d_in[0];
  const float* random_ = (const float*)d_in[1];
  const float* dit_h   = (const float*)d_in[2];
  const float* feat    = (const float*)d_in[3];
  const float* cfg     = (const float*)d_in[4];
  const float* cfgm    = (const float*)d_in[5];
  const float* t_emb   = (const float*)d_in[6];
  const float* dt      = (const float*)d_in[7];
  const float* in_w    = (const float*)d_in[8];
  const float* in_b    = (const float*)d_in[9];
  const float* qkv_w   = (const float*)d_in[10];
  const float* qkv_b   = (const float*)d_in[11];
  const float* o_w     = (const float*)d_in[12];
  const float* gu_w    = (const float*)d_in[13];
  const float* dn_w    = (const float*)d_in[14];
  const float* op_w    = (const float*)d_in[15];
  const float* op_b    = (const float*)d_in[16];

  unsigned* bars = (unsigned*)d_ws;                       // [0, 4096)
  float* hs     = (float*)((char*)d_ws + 4096);           // 18*1024
  float* qkvb   = hs    + ROWS * HID;                     // 18*3072
  float* attnb  = qkvb  + ROWS * 3072;                    // 18*1024
  float* gub    = attnb + ROWS * HID;                     // 18*8192
  float* outtmp = gub   + ROWS * 8192;                    // 512
  float* dout   = (float*)d_out;

  hipMemsetAsync(d_ws, 0, 4096, stream);

  void* args[] = {
    (void*)&step, (void*)&random_, (void*)&dit_h, (void*)&feat, (void*)&cfg,
    (void*)&cfgm, (void*)&t_emb, (void*)&dt, (void*)&in_w, (void*)&in_b,
    (void*)&qkv_w, (void*)&qkv_b, (void*)&o_w, (void*)&gu_w, (void*)&dn_w,
    (void*)&op_w, (void*)&op_b, (void*)&bars,
    (void*)&hs, (void*)&qkvb, (void*)&attnb, (void*)&gub, (void*)&outtmp,
    (void*)&dout
  };
  hipLaunchCooperativeKernel((void*)vox_persist, dim3(NBLK), dim3(512),
                             args, 0, stream);
}